// Round 3
// baseline (683.777 us; speedup 1.0000x reference)
//
#include <hip/hip_runtime.h>

#define NACT 200000
#define MPAD 200064          // ceil(NACT/128)*128
#define NBLK 1563            // MPAD/128
#define KOFF 27

#define SCAT_B 21094         // ceil(27*200000/256)
#define CAST_B 25001         // ceil((200000+1)*32/256)
#define PREPW_B 1728         // 27*16384/256

typedef __bf16 bf16x8 __attribute__((ext_vector_type(8)));
typedef __bf16 bf16x4 __attribute__((ext_vector_type(4)));
typedef float f32x4 __attribute__((ext_vector_type(4)));

__device__ __forceinline__ void async_load16(const void* g, void* l) {
  __builtin_amdgcn_global_load_lds(
      (__attribute__((address_space(1))) void*)g,
      (__attribute__((address_space(3))) void*)l, 16, 0, 0);
}

// ---------------- fused prep: rulebook scatter + feature cast + W swizzle ----------
// G pre-filled with 0x7F7F7F7F sentinel via hipMemsetAsync; GEMM clamps with min().
// B2 layout (fragment-major): elem((k,cc,n,e)) = W[k][cc*8+e][n]  -> index
// ((k*16+cc)*128+n)*8+e. A wave's B-fragment load is then fully coalesced.
__global__ void prep_all(const int* __restrict__ ii, const int* __restrict__ oi,
                         int* __restrict__ G,
                         const float* __restrict__ F, __bf16* __restrict__ X,
                         const float* __restrict__ W1, const float* __restrict__ W2,
                         __bf16* __restrict__ T1, __bf16* __restrict__ T2) {
  int b = blockIdx.x;
  if (b < SCAT_B) {
    int i = b * 256 + threadIdx.x;
    if (i < KOFF * NACT) {
      int o = oi[i];
      if (o < NACT) G[(i / NACT) * MPAD + o] = ii[i];  // skip pads (o==NACT)
    }
  } else if (b < SCAT_B + CAST_B) {
    int i = (b - SCAT_B) * 256 + threadIdx.x;
    if (i < (NACT + 1) * 32) {
      float4 v = (i < NACT * 32) ? ((const float4*)F)[i] : make_float4(0.f, 0.f, 0.f, 0.f);
      bf16x4 o = {(__bf16)v.x, (__bf16)v.y, (__bf16)v.z, (__bf16)v.w};
      *(bf16x4*)(X + (i << 2)) = o;
    }
  } else {
    int i = (b - SCAT_B - CAST_B) * 256 + threadIdx.x;   // < 27*16384
    int kk = i >> 14, r = i & 16383, cc = r >> 10, n = (r >> 3) & 127, e = r & 7;
    int src = (kk << 14) + ((cc << 3) + e) * 128 + n;    // W[kk][cc*8+e][n]
    T1[i] = (__bf16)W1[src];
    T2[i] = (__bf16)W2[src];
  }
}

// ---------------- gather-GEMM: Y[m,:] = sum_k X[G[k][m],:] @ W[k] ----------------
// 128x128 tile, 4 waves (2x2 of 64x64), BK=64. A staged via global_load_lds with
// XOR-8 swizzle (conflict-free, measured). B fragments loaded DIRECTLY global->VGPR
// from the fragment-major B2 (L1/L2-resident broadcast) -- halves LDS traffic.
__global__ __launch_bounds__(256, 3) void gemm_gather(
    const __bf16* __restrict__ X,   // [NACT+1][128], row NACT = 0
    const __bf16* __restrict__ B2,  // [27][16][128][8] fragment-major
    const int* __restrict__ G,      // [27][MPAD], sentinel-clamped
    __bf16* __restrict__ Y,         // [MPAD][128] bf16
    float* __restrict__ Pst)        // [256][NBLK] BN stats partials
{
  __shared__ __bf16 Alds[128 * 64];   // 16 KB
  const int t = threadIdx.x;
  const int lane = t & 63;
  const int w = t >> 6;
  const int wm = (w & 1) << 6;
  const int wn = (w >> 1) << 6;
  const int m_base = blockIdx.x << 7;
  const int r0 = t >> 3;   // staging row group 0..31
  const int scb = t & 7;   // lds 16B-chunk slot within row
  const int l15 = lane & 15;
  const int q4 = lane >> 4;

  f32x4 acc[4][4];
#pragma unroll
  for (int i = 0; i < 4; ++i)
#pragma unroll
    for (int j = 0; j < 4; ++j) acc[i][j] = (f32x4){0.f, 0.f, 0.f, 0.f};

  for (int kk = 0; kk < KOFF; ++kk) {
    int rowA[4];
#pragma unroll
    for (int j = 0; j < 4; ++j) {
      int g = G[kk * MPAD + m_base + r0 + j * 32];
      rowA[j] = g < NACT ? g : NACT;   // clamp sentinel / pads to zero-row
    }
#pragma unroll
    for (int s = 0; s < 2; ++s) {
      const int c0 = s << 6;
      __syncthreads();   // previous compute finished before LDS overwrite
#pragma unroll
      for (int j = 0; j < 4; ++j) {
        const int r = r0 + j * 32;
        const int gcb = scb ^ (r & 7);   // XOR-swizzle: lds slot scb <- global chunk gcb
        async_load16(X + (rowA[j] << 7) + c0 + (gcb << 3), &Alds[(((r << 3) + scb) << 3)]);
      }
      // B frags ks=0 issued before the barrier: drain covers their latency
      const __bf16* bbase = B2 + (((kk << 4) + (s << 3) + q4) << 10) + ((wn + l15) << 3);
      bf16x8 b0[4], b1[4];
#pragma unroll
      for (int ni = 0; ni < 4; ++ni)
        b0[ni] = *(const bf16x8*)(bbase + (ni << 7));          // cc = s*8 + 0*4 + q4
      __syncthreads();   // vmcnt(0) drain (A staging + B frags)
#pragma unroll
      for (int ni = 0; ni < 4; ++ni)
        b1[ni] = *(const bf16x8*)(bbase + (1 << 12) + (ni << 7));  // cc = s*8 + 4 + q4
      // ks = 0
      {
        bf16x8 af[4];
#pragma unroll
        for (int mi = 0; mi < 4; ++mi) {
          const int r = wm + mi * 16 + l15;
          af[mi] = *(const bf16x8*)&Alds[(((r << 3) + (q4 ^ (r & 7))) << 3)];
        }
#pragma unroll
        for (int mi = 0; mi < 4; ++mi)
#pragma unroll
          for (int ni = 0; ni < 4; ++ni)
            acc[mi][ni] = __builtin_amdgcn_mfma_f32_16x16x32_bf16(
                af[mi], b0[ni], acc[mi][ni], 0, 0, 0);
      }
      // ks = 1 (b1 latency hidden behind ks=0 MFMAs)
      {
        bf16x8 af[4];
        const int cb0 = 4 + q4;
#pragma unroll
        for (int mi = 0; mi < 4; ++mi) {
          const int r = wm + mi * 16 + l15;
          af[mi] = *(const bf16x8*)&Alds[(((r << 3) + (cb0 ^ (r & 7))) << 3)];
        }
#pragma unroll
        for (int mi = 0; mi < 4; ++mi)
#pragma unroll
          for (int ni = 0; ni < 4; ++ni)
            acc[mi][ni] = __builtin_amdgcn_mfma_f32_16x16x32_bf16(
                af[mi], b1[ni], acc[mi][ni], 0, 0, 0);
      }
    }
  }

  // ---- epilogue 1: bf16 Y stores (C/D layout: col=lane&15, row=quad*4+reg) ----
#pragma unroll
  for (int mi = 0; mi < 4; ++mi) {
#pragma unroll
    for (int ni = 0; ni < 4; ++ni) {
      const int col = wn + ni * 16 + l15;
#pragma unroll
      for (int rg = 0; rg < 4; ++rg) {
        const int row = m_base + wm + mi * 16 + (q4 << 2) + rg;
        Y[(row << 7) + col] = (__bf16)acc[mi][ni][rg];
      }
    }
  }

  // ---- epilogue 2: BN stats partials (padding rows are zero -> harmless) ----
  float s[4], s2[4];
#pragma unroll
  for (int ni = 0; ni < 4; ++ni) {
    float a = 0.f, b = 0.f;
#pragma unroll
    for (int mi = 0; mi < 4; ++mi)
#pragma unroll
      for (int rg = 0; rg < 4; ++rg) {
        float v = acc[mi][ni][rg];
        a += v; b += v * v;
      }
    s[ni] = a; s2[ni] = b;
  }
#pragma unroll
  for (int ni = 0; ni < 4; ++ni) {
    s[ni]  += __shfl_xor(s[ni], 16);  s[ni]  += __shfl_xor(s[ni], 32);
    s2[ni] += __shfl_xor(s2[ni], 16); s2[ni] += __shfl_xor(s2[ni], 32);
  }
  float* sc = (float*)Alds;   // 512 floats scratch
  __syncthreads();
  if (q4 == 0) {
#pragma unroll
    for (int ni = 0; ni < 4; ++ni) {
      sc[(w << 6) + ni * 16 + l15]       = s[ni];
      sc[256 + (w << 6) + ni * 16 + l15] = s2[ni];
    }
  }
  __syncthreads();
  {
    const int kind = t >> 7, col = t & 127;
    const int w1 = (col >> 6) << 1;
    const float v = sc[kind * 256 + (w1 << 6) + (col & 63)] +
                    sc[kind * 256 + ((w1 + 1) << 6) + (col & 63)];
    Pst[(size_t)t * NBLK + blockIdx.x] = v;
  }
}

// ---------------- stats tree-reduce fused with BN coeffs ----------------
__global__ void stats_coeffs(const float* __restrict__ P, const float* __restrict__ gamma,
                             const float* __restrict__ beta, float* __restrict__ co) {
  int c = blockIdx.x;  // 0..127
  float s = 0.f, s2 = 0.f;
  for (int i = threadIdx.x; i < NBLK; i += 256) {
    s  += P[(size_t)c * NBLK + i];
    s2 += P[(size_t)(128 + c) * NBLK + i];
  }
  for (int off = 32; off; off >>= 1) {
    s  += __shfl_down(s, off);
    s2 += __shfl_down(s2, off);
  }
  __shared__ float ls[8];
  if ((threadIdx.x & 63) == 0) {
    ls[threadIdx.x >> 6]     = s;
    ls[4 + (threadIdx.x >> 6)] = s2;
  }
  __syncthreads();
  if (threadIdx.x == 0) {
    float S  = ls[0] + ls[1] + ls[2] + ls[3];
    float S2 = ls[4] + ls[5] + ls[6] + ls[7];
    float m = S * (1.f / NACT);
    float v = S2 * (1.f / NACT) - m * m;
    float scale = gamma[c] * rsqrtf(v + 1e-4f);
    co[c] = scale;
    co[128 + c] = beta[c] - m * scale;
  }
}

__global__ void bn_relu_cast(const __bf16* __restrict__ Y, const float* __restrict__ co,
                             __bf16* __restrict__ X2) {
  int i = blockIdx.x * 256 + threadIdx.x;   // 8-elem chunks, (NACT+1)*16
  if (i >= (NACT + 1) * 16) return;
  bf16x8 o;
  if (i < NACT * 16) {
    bf16x8 v = ((const bf16x8*)Y)[i];
    int cg = (i & 15) << 3;
#pragma unroll
    for (int e = 0; e < 8; ++e) {
      float x = fmaf((float)v[e], co[cg + e], co[128 + cg + e]);
      o[e] = (__bf16)fmaxf(x, 0.f);
    }
  } else {
#pragma unroll
    for (int e = 0; e < 8; ++e) o[e] = (__bf16)0.f;   // keep zero-row zero
  }
  ((bf16x8*)X2)[i] = o;
}

__global__ void bn_add_relu(const __bf16* __restrict__ Y, const float* __restrict__ co,
                            const float* __restrict__ F, float* __restrict__ O) {
  int i = blockIdx.x * 256 + threadIdx.x;   // 8-elem chunks, NACT*16
  if (i >= NACT * 16) return;
  bf16x8 v = ((const bf16x8*)Y)[i];
  float4 f0 = ((const float4*)F)[2 * i];
  float4 f1 = ((const float4*)F)[2 * i + 1];
  int cg = (i & 15) << 3;
  float4 o0, o1;
  o0.x = fmaxf(fmaf((float)v[0], co[cg + 0], co[128 + cg + 0]) + f0.x, 0.f);
  o0.y = fmaxf(fmaf((float)v[1], co[cg + 1], co[128 + cg + 1]) + f0.y, 0.f);
  o0.z = fmaxf(fmaf((float)v[2], co[cg + 2], co[128 + cg + 2]) + f0.z, 0.f);
  o0.w = fmaxf(fmaf((float)v[3], co[cg + 3], co[128 + cg + 3]) + f0.w, 0.f);
  o1.x = fmaxf(fmaf((float)v[4], co[cg + 4], co[128 + cg + 4]) + f1.x, 0.f);
  o1.y = fmaxf(fmaf((float)v[5], co[cg + 5], co[128 + cg + 5]) + f1.y, 0.f);
  o1.z = fmaxf(fmaf((float)v[6], co[cg + 6], co[128 + cg + 6]) + f1.z, 0.f);
  o1.w = fmaxf(fmaf((float)v[7], co[cg + 7], co[128 + cg + 7]) + f1.w, 0.f);
  ((float4*)O)[2 * i] = o0;
  ((float4*)O)[2 * i + 1] = o1;
}

// ---------------- launcher ----------------
extern "C" void kernel_launch(void* const* d_in, const int* in_sizes, int n_in,
                              void* d_out, int out_size, void* d_ws, size_t ws_size,
                              hipStream_t stream) {
  const float* features = (const float*)d_in[0];
  const float* W1       = (const float*)d_in[1];
  const float* gamma1   = (const float*)d_in[2];
  const float* beta1    = (const float*)d_in[3];
  const float* W2       = (const float*)d_in[4];
  const float* gamma2   = (const float*)d_in[5];
  const float* beta2    = (const float*)d_in[6];
  const int* in_idx     = (const int*)d_in[7];
  const int* out_idx    = (const int*)d_in[8];

  char* ws = (char*)d_ws;
  size_t off = 0;
  int*    G   = (int*)(ws + off);    off += (size_t)KOFF * MPAD * 4;          // 21.6 MB
  __bf16* X   = (__bf16*)(ws + off); off += (size_t)(NACT + 1) * 128 * 2;     // 51.2 MB
  __bf16* T1  = (__bf16*)(ws + off); off += (size_t)KOFF * 128 * 128 * 2;     // 0.88 MB
  __bf16* T2  = (__bf16*)(ws + off); off += (size_t)KOFF * 128 * 128 * 2;     // 0.88 MB
  __bf16* Y   = (__bf16*)(ws + off); off += (size_t)MPAD * 128 * 2;           // 51.2 MB
  float*  Pst = (float*)(ws + off);  off += (size_t)256 * NBLK * 4;           // 1.6 MB
  float*  st  = (float*)(ws + off);  off += 4096;   // coeffs1 @0, coeffs2 @256

  hipMemsetAsync(G, 0x7F, (size_t)KOFF * MPAD * 4, stream);  // sentinel > NACT

  prep_all<<<SCAT_B + CAST_B + PREPW_B, 256, 0, stream>>>(
      in_idx, out_idx, G, features, X, W1, W2, T1, T2);

  gemm_gather<<<NBLK, 256, 0, stream>>>(X, T1, G, Y, Pst);
  stats_coeffs<<<128, 256, 0, stream>>>(Pst, gamma1, beta1, st);
  bn_relu_cast<<<((NACT + 1) * 16 + 255) / 256, 256, 0, stream>>>(Y, st, X);

  gemm_gather<<<NBLK, 256, 0, stream>>>(X, T2, G, Y, Pst);
  stats_coeffs<<<128, 256, 0, stream>>>(Pst, gamma2, beta2, st + 256);
  bn_add_relu<<<(NACT * 16 + 255) / 256, 256, 0, stream>>>(Y, st + 256, features, (float*)d_out);
}

// Round 4
// 614.847 us; speedup vs baseline: 1.1121x; 1.1121x over previous
//
#include <hip/hip_runtime.h>

#define NACT 200000
#define MPAD 200192          // ceil(NACT/256)*256
#define NBLK 782             // MPAD/256
#define KOFF 27

#define SCAT_B 21094         // ceil(27*200000/256)
#define CAST_B 25001         // ceil((200000+1)*32/256)
#define PREPW_B 1728         // 27*16384/256

typedef __bf16 bf16x8 __attribute__((ext_vector_type(8)));
typedef __bf16 bf16x4 __attribute__((ext_vector_type(4)));
typedef float f32x4 __attribute__((ext_vector_type(4)));

__device__ __forceinline__ void async_load16(const void* g, void* l) {
  __builtin_amdgcn_global_load_lds(
      (__attribute__((address_space(1))) void*)g,
      (__attribute__((address_space(3))) void*)l, 16, 0, 0);
}

// ---------------- fused prep: rulebook scatter + feature cast + W transpose -------
// G pre-filled with 0x7F7F7F7F sentinel via hipMemsetAsync; GEMM clamps to zero-row.
__global__ void prep_all(const int* __restrict__ ii, const int* __restrict__ oi,
                         int* __restrict__ G,
                         const float* __restrict__ F, __bf16* __restrict__ X,
                         const float* __restrict__ W1, const float* __restrict__ W2,
                         __bf16* __restrict__ T1, __bf16* __restrict__ T2) {
  int b = blockIdx.x;
  if (b < SCAT_B) {
    int i = b * 256 + threadIdx.x;
    if (i < KOFF * NACT) {
      int o = oi[i];
      if (o < NACT) G[(i / NACT) * MPAD + o] = ii[i];  // skip pads (o==NACT)
    }
  } else if (b < SCAT_B + CAST_B) {
    int i = (b - SCAT_B) * 256 + threadIdx.x;
    if (i < (NACT + 1) * 32) {
      float4 v = (i < NACT * 32) ? ((const float4*)F)[i] : make_float4(0.f, 0.f, 0.f, 0.f);
      bf16x4 o = {(__bf16)v.x, (__bf16)v.y, (__bf16)v.z, (__bf16)v.w};
      *(bf16x4*)(X + (i << 2)) = o;
    }
  } else {
    int i = (b - SCAT_B - CAST_B) * 256 + threadIdx.x;   // WT[k][n][c] = W[k][c][n]
    int k = i >> 14, r = i & 16383, n = r >> 7, c = r & 127;
    int src = (k << 14) + (c << 7) + n;
    T1[i] = (__bf16)W1[src];
    T2[i] = (__bf16)W2[src];
  }
}

// ---------------- gather-GEMM: Y[m,:] = sum_k X[G[k][m],:] @ W[k] ----------------
// 256x128 block tile, 4 waves each 64x128 (acc 4x8), BK=64, XOR-8 LDS swizzle.
// Bigger wave tile -> 43.7 FLOP per LDS-read-byte (vs 32 at 64x64) and half the
// barriers per FLOP. B stays in LDS (R3's direct-global B regressed: L2 latency).
__global__ __launch_bounds__(256, 2) void gemm_gather(
    const __bf16* __restrict__ X,   // [NACT+1][128], row NACT = 0
    const __bf16* __restrict__ WT,  // [27][128][128] : WT[k][n][c]
    const int* __restrict__ G,      // [27][MPAD], sentinel-clamped
    __bf16* __restrict__ Y,         // [MPAD][128] bf16
    float* __restrict__ Pst)        // [256][NBLK] BN stats partials
{
  __shared__ __bf16 Alds[256 * 64];   // 32 KB
  __shared__ __bf16 Blds[128 * 64];   // 16 KB
  const int t = threadIdx.x;
  const int lane = t & 63;
  const int w = t >> 6;
  const int wm = w << 6;              // wave's 64-row band
  const int m_base = blockIdx.x << 8;
  const int r0 = t >> 3;   // staging row group 0..31
  const int scb = t & 7;   // lds 16B-chunk slot within row
  const int l15 = lane & 15;
  const int q4 = lane >> 4;

  f32x4 acc[4][8];
#pragma unroll
  for (int i = 0; i < 4; ++i)
#pragma unroll
    for (int j = 0; j < 8; ++j) acc[i][j] = (f32x4){0.f, 0.f, 0.f, 0.f};

  for (int kk = 0; kk < KOFF; ++kk) {
    int rowA[8];
#pragma unroll
    for (int j = 0; j < 8; ++j) {
      int g = G[kk * MPAD + m_base + r0 + j * 32];
      rowA[j] = g < NACT ? g : NACT;   // clamp sentinel / pads to zero-row
    }
    const __bf16* wb = WT + (kk << 14);
#pragma unroll
    for (int s = 0; s < 2; ++s) {
      const int c0 = s << 6;
      __syncthreads();   // previous compute finished before LDS overwrite
#pragma unroll
      for (int j = 0; j < 8; ++j) {
        const int r = r0 + j * 32;
        const int gcb = scb ^ (r & 7);   // XOR-swizzle: slot scb <- global chunk gcb
        async_load16(X + (rowA[j] << 7) + c0 + (gcb << 3), &Alds[(((r << 3) + scb) << 3)]);
      }
#pragma unroll
      for (int j = 0; j < 4; ++j) {
        const int r = r0 + j * 32;       // B rows 0..127
        const int gcb = scb ^ (r & 7);
        async_load16(wb + (r << 7) + c0 + (gcb << 3), &Blds[(((r << 3) + scb) << 3)]);
      }
      __syncthreads();   // vmcnt(0) drain for global_load_lds
#pragma unroll
      for (int ks = 0; ks < 2; ++ks) {
        const int cb0 = (ks << 2) + q4;
        bf16x8 af[4];
#pragma unroll
        for (int mi = 0; mi < 4; ++mi) {
          const int r = wm + mi * 16 + l15;
          af[mi] = *(const bf16x8*)&Alds[(((r << 3) + (cb0 ^ (r & 7))) << 3)];
        }
#pragma unroll
        for (int nh = 0; nh < 2; ++nh) {   // B in halves to limit register pressure
          bf16x8 bfr[4];
#pragma unroll
          for (int nn = 0; nn < 4; ++nn) {
            const int r = (nh * 4 + nn) * 16 + l15;
            bfr[nn] = *(const bf16x8*)&Blds[(((r << 3) + (cb0 ^ (r & 7))) << 3)];
          }
#pragma unroll
          for (int mi = 0; mi < 4; ++mi)
#pragma unroll
            for (int nn = 0; nn < 4; ++nn)
              acc[mi][nh * 4 + nn] = __builtin_amdgcn_mfma_f32_16x16x32_bf16(
                  af[mi], bfr[nn], acc[mi][nh * 4 + nn], 0, 0, 0);
        }
      }
    }
  }

  // ---- epilogue 1: bf16 Y stores (C/D layout: col=lane&15, row=quad*4+reg) ----
#pragma unroll
  for (int mi = 0; mi < 4; ++mi) {
#pragma unroll
    for (int ni = 0; ni < 8; ++ni) {
      const int col = ni * 16 + l15;
#pragma unroll
      for (int rg = 0; rg < 4; ++rg) {
        const int row = m_base + wm + mi * 16 + (q4 << 2) + rg;
        Y[(row << 7) + col] = (__bf16)acc[mi][ni][rg];
      }
    }
  }

  // ---- epilogue 2: BN stats partials (padding rows are zero -> harmless) ----
  float s[8], s2[8];
#pragma unroll
  for (int ni = 0; ni < 8; ++ni) {
    float a = 0.f, b = 0.f;
#pragma unroll
    for (int mi = 0; mi < 4; ++mi)
#pragma unroll
      for (int rg = 0; rg < 4; ++rg) {
        float v = acc[mi][ni][rg];
        a += v; b += v * v;
      }
    s[ni] = a; s2[ni] = b;
  }
#pragma unroll
  for (int ni = 0; ni < 8; ++ni) {
    s[ni]  += __shfl_xor(s[ni], 16);  s[ni]  += __shfl_xor(s[ni], 32);
    s2[ni] += __shfl_xor(s2[ni], 16); s2[ni] += __shfl_xor(s2[ni], 32);
  }
  float* sc = (float*)Alds;   // 1024 floats scratch
  __syncthreads();
  if (q4 == 0) {
#pragma unroll
    for (int ni = 0; ni < 8; ++ni) {
      const int col = ni * 16 + l15;
      sc[(w << 7) + col]       = s[ni];
      sc[512 + (w << 7) + col] = s2[ni];
    }
  }
  __syncthreads();
  {
    const int kind = t >> 7, col = t & 127;
    const float* p = sc + kind * 512 + col;
    Pst[(size_t)t * NBLK + blockIdx.x] = p[0] + p[128] + p[256] + p[384];
  }
}

// ---------------- stats tree-reduce fused with BN coeffs ----------------
__global__ void stats_coeffs(const float* __restrict__ P, const float* __restrict__ gamma,
                             const float* __restrict__ beta, float* __restrict__ co) {
  int c = blockIdx.x;  // 0..127
  float s = 0.f, s2 = 0.f;
  for (int i = threadIdx.x; i < NBLK; i += 256) {
    s  += P[(size_t)c * NBLK + i];
    s2 += P[(size_t)(128 + c) * NBLK + i];
  }
  for (int off = 32; off; off >>= 1) {
    s  += __shfl_down(s, off);
    s2 += __shfl_down(s2, off);
  }
  __shared__ float ls[8];
  if ((threadIdx.x & 63) == 0) {
    ls[threadIdx.x >> 6]       = s;
    ls[4 + (threadIdx.x >> 6)] = s2;
  }
  __syncthreads();
  if (threadIdx.x == 0) {
    float S  = ls[0] + ls[1] + ls[2] + ls[3];
    float S2 = ls[4] + ls[5] + ls[6] + ls[7];
    float m = S * (1.f / NACT);
    float v = S2 * (1.f / NACT) - m * m;
    float scale = gamma[c] * rsqrtf(v + 1e-4f);
    co[c] = scale;
    co[128 + c] = beta[c] - m * scale;
  }
}

__global__ void bn_relu_cast(const __bf16* __restrict__ Y, const float* __restrict__ co,
                             __bf16* __restrict__ X2) {
  int i = blockIdx.x * 256 + threadIdx.x;   // 8-elem chunks, (NACT+1)*16
  if (i >= (NACT + 1) * 16) return;
  bf16x8 o;
  if (i < NACT * 16) {
    bf16x8 v = ((const bf16x8*)Y)[i];
    int cg = (i & 15) << 3;
#pragma unroll
    for (int e = 0; e < 8; ++e) {
      float x = fmaf((float)v[e], co[cg + e], co[128 + cg + e]);
      o[e] = (__bf16)fmaxf(x, 0.f);
    }
  } else {
#pragma unroll
    for (int e = 0; e < 8; ++e) o[e] = (__bf16)0.f;   // keep zero-row zero
  }
  ((bf16x8*)X2)[i] = o;
}

__global__ void bn_add_relu(const __bf16* __restrict__ Y, const float* __restrict__ co,
                            const float* __restrict__ F, float* __restrict__ O) {
  int i = blockIdx.x * 256 + threadIdx.x;   // 8-elem chunks, NACT*16
  if (i >= NACT * 16) return;
  bf16x8 v = ((const bf16x8*)Y)[i];
  float4 f0 = ((const float4*)F)[2 * i];
  float4 f1 = ((const float4*)F)[2 * i + 1];
  int cg = (i & 15) << 3;
  float4 o0, o1;
  o0.x = fmaxf(fmaf((float)v[0], co[cg + 0], co[128 + cg + 0]) + f0.x, 0.f);
  o0.y = fmaxf(fmaf((float)v[1], co[cg + 1], co[128 + cg + 1]) + f0.y, 0.f);
  o0.z = fmaxf(fmaf((float)v[2], co[cg + 2], co[128 + cg + 2]) + f0.z, 0.f);
  o0.w = fmaxf(fmaf((float)v[3], co[cg + 3], co[128 + cg + 3]) + f0.w, 0.f);
  o1.x = fmaxf(fmaf((float)v[4], co[cg + 4], co[128 + cg + 4]) + f1.x, 0.f);
  o1.y = fmaxf(fmaf((float)v[5], co[cg + 5], co[128 + cg + 5]) + f1.y, 0.f);
  o1.z = fmaxf(fmaf((float)v[6], co[cg + 6], co[128 + cg + 6]) + f1.z, 0.f);
  o1.w = fmaxf(fmaf((float)v[7], co[cg + 7], co[128 + cg + 7]) + f1.w, 0.f);
  ((float4*)O)[2 * i] = o0;
  ((float4*)O)[2 * i + 1] = o1;
}

// ---------------- launcher ----------------
extern "C" void kernel_launch(void* const* d_in, const int* in_sizes, int n_in,
                              void* d_out, int out_size, void* d_ws, size_t ws_size,
                              hipStream_t stream) {
  const float* features = (const float*)d_in[0];
  const float* W1       = (const float*)d_in[1];
  const float* gamma1   = (const float*)d_in[2];
  const float* beta1    = (const float*)d_in[3];
  const float* W2       = (const float*)d_in[4];
  const float* gamma2   = (const float*)d_in[5];
  const float* beta2    = (const float*)d_in[6];
  const int* in_idx     = (const int*)d_in[7];
  const int* out_idx    = (const int*)d_in[8];

  char* ws = (char*)d_ws;
  size_t off = 0;
  int*    G   = (int*)(ws + off);    off += (size_t)KOFF * MPAD * 4;          // 21.6 MB
  __bf16* X   = (__bf16*)(ws + off); off += (size_t)(NACT + 1) * 128 * 2;     // 51.2 MB
  __bf16* T1  = (__bf16*)(ws + off); off += (size_t)KOFF * 128 * 128 * 2;     // 0.88 MB
  __bf16* T2  = (__bf16*)(ws + off); off += (size_t)KOFF * 128 * 128 * 2;     // 0.88 MB
  __bf16* Y   = (__bf16*)(ws + off); off += (size_t)MPAD * 128 * 2;           // 51.2 MB
  float*  Pst = (float*)(ws + off);  off += (size_t)256 * NBLK * 4;           // 0.8 MB
  float*  st  = (float*)(ws + off);  off += 4096;   // coeffs1 @0, coeffs2 @256

  hipMemsetAsync(G, 0x7F, (size_t)KOFF * MPAD * 4, stream);  // sentinel > NACT

  prep_all<<<SCAT_B + CAST_B + PREPW_B, 256, 0, stream>>>(
      in_idx, out_idx, G, features, X, W1, W2, T1, T2);

  gemm_gather<<<NBLK, 256, 0, stream>>>(X, T1, G, Y, Pst);
  stats_coeffs<<<128, 256, 0, stream>>>(Pst, gamma1, beta1, st);
  bn_relu_cast<<<((NACT + 1) * 16 + 255) / 256, 256, 0, stream>>>(Y, st, X);

  gemm_gather<<<NBLK, 256, 0, stream>>>(X, T2, G, Y, Pst);
  stats_coeffs<<<128, 256, 0, stream>>>(Pst, gamma2, beta2, st + 256);
  bn_add_relu<<<(NACT * 16 + 255) / 256, 256, 0, stream>>>(Y, st + 256, features, (float*)d_out);
}